// Round 11
// baseline (190.042 us; speedup 1.0000x reference)
//
#include <hip/hip_runtime.h>

#define NN 4096
#define DD 512
#define HH 8
#define FF 64
#define LRELU_ALPHA 0.2f
#define SP 72   // LDS row stride in bf16 elems

typedef __attribute__((ext_vector_type(8))) short bf16x8;
typedef __attribute__((ext_vector_type(4))) float f32x4;

__device__ __forceinline__ float f4c(const float4& v, int k) {
    return k == 0 ? v.x : (k == 1 ? v.y : (k == 2 ? v.z : v.w));
}
__device__ __forceinline__ void f4s(float4& v, int k, float x) {
    if (k == 0) v.x = x; else if (k == 1) v.y = x; else if (k == 2) v.z = x; else v.w = x;
}
__device__ __forceinline__ unsigned short f2bf(float x) {   // RNE float->bf16
    unsigned u = __float_as_uint(x);
    return (unsigned short)((u + 0x7fffu + ((u >> 16) & 1u)) >> 16);
}
__device__ __forceinline__ float bf2f(unsigned short h) {
    return __uint_as_float(((unsigned)h) << 16);
}
// monotone float<->uint key for atomicMax on arbitrary-sign floats
__device__ __forceinline__ unsigned fkey(float x) {
    unsigned u = __float_as_uint(x);
    return (u & 0x80000000u) ? ~u : (u | 0x80000000u);
}
__device__ __forceinline__ float funkey(unsigned k) {
    unsigned u = (k & 0x80000000u) ? (k ^ 0x80000000u) : ~k;
    return __uint_as_float(u);
}
// CK-style barrier: drain LDS counts only; in-flight global->register loads survive.
__device__ __forceinline__ void sync_lds() {
    asm volatile("s_waitcnt lgkmcnt(0)\n\ts_barrier" ::: "memory");
}

// ================= Kernel 1: fused prep =================
// [0,4096)     : adjpack
// [4096,4160)  : split+transpose W -> wt_hi/wt_lo [h][f][d]
// 4160         : zero mxkey + hpsum
__global__ __launch_bounds__(256) void k_prep(const int* __restrict__ adj,
                                              const float* __restrict__ W,
                                              unsigned* __restrict__ adjw,
                                              unsigned short* __restrict__ wt_hi,
                                              unsigned short* __restrict__ wt_lo,
                                              unsigned* __restrict__ mxkey,
                                              float* __restrict__ hpsum) {
    __shared__ float tile[64][65];
    int b = blockIdx.x, t = threadIdx.x;
    if (b < 4096) {
        int lane = t & 63;
        #pragma unroll
        for (int i = 0; i < 16; i++) {
            int tid = ((b * 16 + i) << 8) + t;
            unsigned long long mask = __ballot(adj[tid] > 0);
            if (lane == 0) {
                int base = tid >> 5;
                adjw[base] = (unsigned)mask;
                adjw[base + 1] = (unsigned)(mask >> 32);
            }
        }
    } else if (b < 4160) {
        int idx = b - 4096;
        int h = idx >> 3;
        int d0 = (idx & 7) * 64;
        #pragma unroll
        for (int kidx = 0; kidx < 4; kidx++) {
            int id = t + 256 * kidx;
            int dd = id >> 4, f4i = (id & 15) * 4;
            float4 v = *(const float4*)(W + ((size_t)(h * DD + d0 + dd)) * FF + f4i);
            tile[dd][f4i] = v.x; tile[dd][f4i + 1] = v.y;
            tile[dd][f4i + 2] = v.z; tile[dd][f4i + 3] = v.w;
        }
        __syncthreads();
        int f = t >> 2, c = (t & 3) * 16;
        union { unsigned short s[16]; uint4 v[2]; } hb, lb;
        #pragma unroll
        for (int q = 0; q < 16; q++) {
            float v = tile[c + q][f];
            unsigned short hi = f2bf(v);
            hb.s[q] = hi;
            lb.s[q] = f2bf(v - bf2f(hi));
        }
        uint4* dh = (uint4*)(wt_hi + ((size_t)h * FF + f) * DD + d0 + c);
        uint4* dl = (uint4*)(wt_lo + ((size_t)h * FF + f) * DD + d0 + c);
        dh[0] = hb.v[0]; dh[1] = hb.v[1];
        dl[0] = lb.v[0]; dl[1] = lb.v[1];
    } else {
        if (t < 16) mxkey[t] = 0u;
        hpsum[t] = 0.f;
        hpsum[t + 256] = 0.f;
    }
}

// ================= Kernel 2: hp GEMM, 3-stage pipelined K-loop ========
// Emits hpT_hi, fs/fd, maxfd atomic, hpsum column-sum atomic. grid (64, 8).
__global__ __launch_bounds__(256) void k_hp_mfma(const float* __restrict__ hmat,
                                                 const unsigned short* __restrict__ whi,
                                                 const unsigned short* __restrict__ wlo,
                                                 const float* __restrict__ a,
                                                 unsigned short* __restrict__ hpT_hi,
                                                 float* __restrict__ fs,
                                                 float* __restrict__ fd,
                                                 float* __restrict__ hpsum,
                                                 unsigned* __restrict__ mxkey) {
    __shared__ char smem[4 * 64 * SP * 2];   // 36864 B
    unsigned short* ah = (unsigned short*)smem;
    unsigned short* al = ah + 64 * SP;
    unsigned short* bh = al + 64 * SP;
    unsigned short* bl = bh + 64 * SP;

    int t = threadIdx.x;
    int h = blockIdx.y;
    int n0 = blockIdx.x * 64;
    int lane = t & 63;
    int w = t >> 6;
    int R0 = (w >> 1) * 32, F0 = (w & 1) * 32;
    int am = lane & 15, aq = lane >> 4;
    int sr = t >> 2, sc = (t & 3) * 16;

    const float* gha = hmat + (size_t)(n0 + sr) * DD;
    const unsigned short* gbh = whi + ((size_t)h * FF + sr) * DD;
    const unsigned short* gbl = wlo + ((size_t)h * FF + sr) * DD;

    // pipeline registers
    float4 p0, p1, p2, p3;
    uint4 w0, w1, x0, x1;
    auto gload = [&](int kk) {
        p0 = *(const float4*)(gha + kk + sc);
        p1 = *(const float4*)(gha + kk + sc + 4);
        p2 = *(const float4*)(gha + kk + sc + 8);
        p3 = *(const float4*)(gha + kk + sc + 12);
        const uint4* s2 = (const uint4*)(gbh + kk + sc);
        const uint4* s3 = (const uint4*)(gbl + kk + sc);
        w0 = s2[0]; w1 = s2[1]; x0 = s3[0]; x1 = s3[1];
    };
    auto wstage = [&]() {
        union { unsigned short s[16]; uint4 v[2]; } hb, lb;
        #pragma unroll
        for (int q = 0; q < 16; q++) {
            float v = q < 4 ? f4c(p0, q) : q < 8 ? f4c(p1, q - 4)
                      : q < 12 ? f4c(p2, q - 8) : f4c(p3, q - 12);
            unsigned short hi = f2bf(v);
            hb.s[q] = hi;
            lb.s[q] = f2bf(v - bf2f(hi));
        }
        *(uint4*)(ah + sr * SP + sc) = hb.v[0]; *(uint4*)(ah + sr * SP + sc + 8) = hb.v[1];
        *(uint4*)(al + sr * SP + sc) = lb.v[0]; *(uint4*)(al + sr * SP + sc + 8) = lb.v[1];
        *(uint4*)(bh + sr * SP + sc) = w0; *(uint4*)(bh + sr * SP + sc + 8) = w1;
        *(uint4*)(bl + sr * SP + sc) = x0; *(uint4*)(bl + sr * SP + sc + 8) = x1;
    };

    f32x4 acc[2][2] = {};
    gload(0);
    for (int kk = 0; kk < DD; kk += 64) {
        wstage();                         // waits vmcnt for tile kk only
        if (kk + 64 < DD) gload(kk + 64); // in flight across MFMA + 2 barriers
        sync_lds();
        #pragma unroll
        for (int k2 = 0; k2 < 2; k2++) {
            int ko = k2 * 32 + aq * 8;
            bf16x8 a0h = *(const bf16x8*)(ah + (R0 + am) * SP + ko);
            bf16x8 a1h = *(const bf16x8*)(ah + (R0 + 16 + am) * SP + ko);
            bf16x8 a0l = *(const bf16x8*)(al + (R0 + am) * SP + ko);
            bf16x8 a1l = *(const bf16x8*)(al + (R0 + 16 + am) * SP + ko);
            bf16x8 b0h = *(const bf16x8*)(bh + (F0 + am) * SP + ko);
            bf16x8 b1h = *(const bf16x8*)(bh + (F0 + 16 + am) * SP + ko);
            bf16x8 b0l = *(const bf16x8*)(bl + (F0 + am) * SP + ko);
            bf16x8 b1l = *(const bf16x8*)(bl + (F0 + 16 + am) * SP + ko);
            acc[0][0] = __builtin_amdgcn_mfma_f32_16x16x32_bf16(a0h, b0h, acc[0][0], 0, 0, 0);
            acc[0][1] = __builtin_amdgcn_mfma_f32_16x16x32_bf16(a0h, b1h, acc[0][1], 0, 0, 0);
            acc[1][0] = __builtin_amdgcn_mfma_f32_16x16x32_bf16(a1h, b0h, acc[1][0], 0, 0, 0);
            acc[1][1] = __builtin_amdgcn_mfma_f32_16x16x32_bf16(a1h, b1h, acc[1][1], 0, 0, 0);
            acc[0][0] = __builtin_amdgcn_mfma_f32_16x16x32_bf16(a0h, b0l, acc[0][0], 0, 0, 0);
            acc[0][1] = __builtin_amdgcn_mfma_f32_16x16x32_bf16(a0h, b1l, acc[0][1], 0, 0, 0);
            acc[1][0] = __builtin_amdgcn_mfma_f32_16x16x32_bf16(a1h, b0l, acc[1][0], 0, 0, 0);
            acc[1][1] = __builtin_amdgcn_mfma_f32_16x16x32_bf16(a1h, b1l, acc[1][1], 0, 0, 0);
            acc[0][0] = __builtin_amdgcn_mfma_f32_16x16x32_bf16(a0l, b0h, acc[0][0], 0, 0, 0);
            acc[0][1] = __builtin_amdgcn_mfma_f32_16x16x32_bf16(a0l, b1h, acc[0][1], 0, 0, 0);
            acc[1][0] = __builtin_amdgcn_mfma_f32_16x16x32_bf16(a1l, b0h, acc[1][0], 0, 0, 0);
            acc[1][1] = __builtin_amdgcn_mfma_f32_16x16x32_bf16(a1l, b1h, acc[1][1], 0, 0, 0);
        }
        sync_lds();
    }

    // Epilogue: pack hi/lo to LDS [f][n], store hi, fs/fd, maxfd atomic, hpsum atomic.
    unsigned* tt = (unsigned*)smem;
    float* rs = (float*)(smem + 17408);
    float* rd = rs + 256;
    float* ash = rd + 256;
    if (t < 128) ash[t] = a[h * 2 * FF + t];
    int col = lane & 15, rbase = (lane >> 4) * 4;
    #pragma unroll
    for (int m16 = 0; m16 < 2; m16++) {
        #pragma unroll
        for (int n16 = 0; n16 < 2; n16++) {
            #pragma unroll
            for (int r = 0; r < 4; r++) {
                int nl = R0 + m16 * 16 + rbase + r;
                int f = F0 + n16 * 16 + col;
                float v = acc[m16][n16][r];
                unsigned short hi = f2bf(v);
                unsigned short lo = f2bf(v - bf2f(hi));
                tt[f * 68 + nl] = (unsigned)hi | ((unsigned)lo << 16);
            }
        }
    }
    __syncthreads();
    {
        int f = t >> 2, c = (t & 3) * 16;
        union { unsigned short s[16]; uint4 v[2]; } hb;
        float csum = 0.f;
        #pragma unroll
        for (int q = 0; q < 16; q++) {
            unsigned u = tt[f * 68 + c + q];
            hb.s[q] = (unsigned short)(u & 0xffffu);
            csum += bf2f((unsigned short)(u & 0xffffu)) + bf2f((unsigned short)(u >> 16));
        }
        uint4* dh = (uint4*)(hpT_hi + ((size_t)h * FF + f) * NN + n0 + c);
        dh[0] = hb.v[0]; dh[1] = hb.v[1];
        csum += __shfl_xor(csum, 1);
        csum += __shfl_xor(csum, 2);
        if ((t & 3) == 0) unsafeAtomicAdd(hpsum + h * FF + f, csum);
    }
    {
        int n = t & 63, g = t >> 6;
        float fsp = 0.f, fdp = 0.f;
        #pragma unroll
        for (int q = 0; q < 16; q++) {
            int f = g * 16 + q;
            unsigned u = tt[f * 68 + n];
            float v = bf2f((unsigned short)(u & 0xffffu)) + bf2f((unsigned short)(u >> 16));
            fsp += v * ash[f];
            fdp += v * ash[64 + f];
        }
        rs[g * 64 + n] = fsp;
        rd[g * 64 + n] = fdp;
    }
    __syncthreads();
    if (t < 64) {
        float fdv = rd[t] + rd[64 + t] + rd[128 + t] + rd[192 + t];
        fs[(size_t)h * NN + n0 + t] = rs[t] + rs[64 + t] + rs[128 + t] + rs[192 + t];
        fd[(size_t)h * NN + n0 + t] = fdv;
        unsigned key = fkey(fdv);
        #pragma unroll
        for (int off = 32; off; off >>= 1) key = max(key, (unsigned)__shfl_xor((int)key, off));
        if (t == 0) atomicMax(mxkey + h, key);
    }
}

// ================= Kernel 3: attention — 3-stage pipelined j-loop =============
// grid (NN/32, HH). iter k: mfma(buf k) ; ds_write regs(tile k+1)->buf k+1 ;
// issue gload(tile k+2). sync_lds barrier keeps gloads in flight across it.
__global__ __launch_bounds__(256) void k_attn(const float* __restrict__ fs,
                                              const float* __restrict__ fd,
                                              const unsigned* __restrict__ mxkey,
                                              const unsigned* __restrict__ adjw,
                                              const unsigned short* __restrict__ hpT_hi,
                                              const float* __restrict__ hpsum,
                                              float* __restrict__ outp) {
    __shared__ unsigned short pa[2][32 * SP];
    __shared__ unsigned short hbh[2][64 * SP];
    __shared__ float fss[32], ms[32];

    int t = threadIdx.x;
    int h = blockIdx.y;
    int i0 = blockIdx.x * 32;
    int lane = t & 63;
    int w = t >> 6;

    const float LOG2E = 1.44269504f;
    float mfd = funkey(mxkey[h]);
    if (t < 32) {
        float fsv = fs[(size_t)h * NN + i0 + t];
        fss[t] = fsv;
        float s = fsv + mfd;
        float m = fmaxf(s, LRELU_ALPHA * s);
        ms[t] = m * LOG2E;
    }
    __syncthreads();

    int wr = t >> 3;            // weight row 0..31
    int wc = (t & 7) * 8;       // 8-j chunk
    int sr = t >> 2, sc = (t & 3) * 16;   // hbh staging
    int R0 = (w >> 1) * 16, F0 = (w & 1) * 32;
    int am = lane & 15, aq = lane >> 4;
    f32x4 acc[2] = {};
    f32x4 accl = {};
    bf16x8 bones;
    #pragma unroll
    for (int i = 0; i < 8; i++) bones[i] = (short)0x3f80;   // bf16 1.0

    const unsigned short* gH = hpT_hi + (size_t)h * FF * NN;
    const float* fdh = fd + (size_t)h * NN;
    float fsr = fss[wr], mr = ms[wr];

    // pipeline registers
    uint4 rH0, rH1;
    float4 rF0, rF1;
    unsigned rA;
    auto gload = [&](int j0) {
        const uint4* sh = (const uint4*)(gH + (size_t)sr * NN + j0 + sc);
        rH0 = sh[0]; rH1 = sh[1];
        rF0 = *(const float4*)(fdh + j0 + wc);
        rF1 = *(const float4*)(fdh + j0 + wc + 4);
        rA  = adjw[(size_t)(i0 + wr) * (NN / 32) + ((j0 + wc) >> 5)];
    };
    auto wstage = [&](int buf) {
        *(uint4*)(&hbh[buf][sr * SP + sc]) = rH0;
        *(uint4*)(&hbh[buf][sr * SP + sc + 8]) = rH1;
        unsigned bits = rA >> (wc & 31);
        union { unsigned u[4]; uint4 v; } wb;
        #pragma unroll
        for (int q = 0; q < 2; q++) {
            float4 fdv = q ? rF1 : rF0;
            unsigned eu[4];
            #pragma unroll
            for (int b = 0; b < 4; b++) {
                float s = fsr + f4c(fdv, b);
                float l = fmaxf(s, LRELU_ALPHA * s);
                float e = __builtin_amdgcn_exp2f(__builtin_fmaf(l, LOG2E, -mr));
                e = ((bits >> (q * 4 + b)) & 1u) ? e : 0.f;
                eu[b] = __float_as_uint(e);
            }
            wb.u[q * 2]     = __builtin_amdgcn_perm(eu[1], eu[0], 0x07060302);
            wb.u[q * 2 + 1] = __builtin_amdgcn_perm(eu[3], eu[2], 0x07060302);
        }
        *(uint4*)(&pa[buf][wr * SP + wc]) = wb.v;
    };

    gload(0);
    wstage(0);          // tile 0 -> buf 0
    gload(64);          // tile 1 in flight
    sync_lds();
    for (int k = 0; k < NN / 64; k++) {
        int cur = k & 1;
        #pragma unroll
        for (int k2 = 0; k2 < 2; k2++) {
            int ko = k2 * 32 + aq * 8;
            bf16x8 a0 = *(const bf16x8*)(&pa[cur][(R0 + am) * SP + ko]);
            bf16x8 b0 = *(const bf16x8*)(&hbh[cur][(F0 + am) * SP + ko]);
            bf16x8 b1 = *(const bf16x8*)(&hbh[cur][(F0 + 16 + am) * SP + ko]);
            acc[0] = __builtin_amdgcn_mfma_f32_16x16x32_bf16(a0, b0, acc[0], 0, 0, 0);
            acc[1] = __builtin_amdgcn_mfma_f32_16x16x32_bf16(a0, b1, acc[1], 0, 0, 0);
            accl   = __builtin_amdgcn_mfma_f32_16x16x32_bf16(a0, bones, accl, 0, 0, 0);
        }
        if (k < NN / 64 - 1) {
            wstage(cur ^ 1);                       // tile k+1 (regs loaded at iter k-1)
            if (k < NN / 64 - 2) gload((k + 2) * 64);  // tile k+2 in flight across barrier
        }
        sync_lds();
    }

    // Fused epilogue: l is in accl[r] for the same row as acc[*][r]. Normalize+ELU+store.
    const float invN = 1.0f / NN;
    int col = lane & 15, rbase = (lane >> 4) * 4;
    #pragma unroll
    for (int r = 0; r < 4; r++) {
        int row = i0 + R0 + rbase + r;
        float l = accl[r];
        float rl = 1.f / l;     // l > 0 in non-degenerate case
        #pragma unroll
        for (int n16 = 0; n16 < 2; n16++) {
            int f = F0 + n16 * 16 + col;
            float v;
            if (l > 0.f) v = acc[n16][r] * rl;
            else         v = hpsum[h * FF + f] * invN;   // all-masked row fallback
            v = v > 0.f ? v : __expf(v) - 1.f;
            outp[(size_t)row * (HH * FF) + h * FF + f] = v;
        }
    }
}

extern "C" void kernel_launch(void* const* d_in, const int* in_sizes, int n_in,
                              void* d_out, int out_size, void* d_ws, size_t ws_size,
                              hipStream_t stream) {
    const float* hmat = (const float*)d_in[0];
    const int*   adj  = (const int*)d_in[1];
    const float* W    = (const float*)d_in[2];
    const float* a    = (const float*)d_in[3];
    float* out = (float*)d_out;

    char* ws = (char*)d_ws;
    unsigned short* hpT_hi = (unsigned short*)(ws);                 // 4 MB
    unsigned*       adjw   = (unsigned*)(ws + (4u << 20));          // 2 MB
    unsigned short* wt_hi  = (unsigned short*)(ws + (6u << 20));    // 512 KB
    unsigned short* wt_lo  = (unsigned short*)(ws + (6u << 20) + (512u << 10));
    float* fs    = (float*)(ws + (7u << 20));                       // 128 KB
    float* fd    = (float*)(ws + (7u << 20) + (128u << 10));        // 128 KB
    unsigned* mxkey = (unsigned*)(ws + (7u << 20) + (256u << 10));  // 64 B
    float* hpsum = (float*)(mxkey + 16);                            // 2 KB

    k_prep   <<<dim3(4161),          256, 0, stream>>>(adj, W, adjw, wt_hi, wt_lo,
                                                       mxkey, hpsum);
    k_hp_mfma<<<dim3(64, 8),         256, 0, stream>>>(hmat, wt_hi, wt_lo, a,
                                                       hpT_hi, fs, fd, hpsum, mxkey);
    k_attn   <<<dim3(NN / 32, HH),   256, 0, stream>>>(fs, fd, mxkey, adjw,
                                                       hpT_hi, hpsum, out);
}